// Round 10
// baseline (9325.410 us; speedup 1.0000x reference)
//
#include <hip/hip_runtime.h>
#include <math.h>

typedef _Float16 f16;
typedef _Float16 f16x8 __attribute__((ext_vector_type(8)));
typedef float f32x4 __attribute__((ext_vector_type(4)));

namespace {

constexpr int NT = 256;     // 4 waves; 2 blocks/CU (launch_bounds(,2))
constexpr int M  = 64;      // agents per block
constexpr int HORIZON = 64;

// packed f16 weight layout in d_ws (f16 units); per-chunk fragment order [q][col][j]
constexpr int W2H = 0;        // 65536 f16
constexpr int W2L = 65536;
constexpr int W3H = 131072;
constexpr int W3L = 196608;
constexpr int W1H = 262144;   // 8192 f16 (K padded 13->32)
constexpr int W1L = 270336;   // total 278528 f16 = 544 KB

// ---------------- weight pre-split + pre-pack (once per launch) ----------------
__global__ void prep_kernel(const float* __restrict__ w1, const float* __restrict__ w2,
                            const float* __restrict__ w3, f16* __restrict__ out)
{
    int tid = blockIdx.x * blockDim.x + threadIdx.x;   // 544*256 = 139264 exact
    float v; int hi, lo;
    if (tid < 65536) {          // w2
        int kc = tid >> 13, e2 = tid & 8191;
        int qq = e2 >> 11, col = (e2 >> 3) & 255, j = e2 & 7;
        v = w2[(kc*32 + qq*8 + j)*256 + col];
        hi = W2H + tid; lo = W2L + tid;
    } else if (tid < 131072) {  // w3
        int e = tid - 65536;
        int kc = e >> 13, e2 = e & 8191;
        int qq = e2 >> 11, col = (e2 >> 3) & 255, j = e2 & 7;
        v = w3[(kc*32 + qq*8 + j)*256 + col];
        hi = W3H + e; lo = W3L + e;
    } else {                    // w1, zero-padded to k=32
        int e = tid - 131072;
        int qq = e >> 11, col = (e >> 3) & 255, j = e & 7;
        int k = qq*8 + j;
        v = (k < 13) ? w1[k*256 + col] : 0.f;
        hi = W1H + e; lo = W1L + e;
    }
    f16 h = (f16)v;
    out[hi] = h;
    out[lo] = (f16)(v - (float)h);   // exact residual: 3-term MFMA = fp32-equiv
}

__device__ __forceinline__ void mfma3(f32x4& acc, f16x8 ah, f16x8 al, f16x8 bh, f16x8 bl)
{
    acc = __builtin_amdgcn_mfma_f32_16x16x32_f16(ah, bh, acc, 0, 0, 0);
    acc = __builtin_amdgcn_mfma_f32_16x16x32_f16(al, bh, acc, 0, 0, 0);
    acc = __builtin_amdgcn_mfma_f32_16x16x32_f16(ah, bl, acc, 0, 0, 0);
}

// load this wave's packed B-frags (hi+lo) for one 32-K chunk into slot s: 8x 16B loads
#define FETCH_BP(baseH, baseL, kc, s) do {                                   \
    _Pragma("unroll")                                                        \
    for (int _nt = 0; _nt < 4; ++_nt) {                                      \
        int _off = (kc)*8192 + (q*256 + 64*cq + 16*_nt + lr)*8;              \
        FH[s][_nt] = *(const f16x8*)(wp + (baseH) + _off);                   \
        FL[s][_nt] = *(const f16x8*)(wp + (baseL) + _off);                   \
    }                                                                        \
} while (0)

// one K-chunk: A-frags from hA (swizzled), B-frags straight from slot s
#define GEMM_CHUNK(s, kcl) do {                                              \
    f16x8 _ah[4], _al[4];                                                    \
    _Pragma("unroll")                                                        \
    for (int _mt = 0; _mt < 4; ++_mt) {                                      \
        int _row = 16*_mt + lr;                                              \
        int _off = _row*256 + ((((kcl)*4 + q) ^ (_row & 31)) << 3);          \
        _ah[_mt] = *(const f16x8*)(hA_hi + _off);                            \
        _al[_mt] = *(const f16x8*)(hA_lo + _off);                            \
    }                                                                        \
    _Pragma("unroll")                                                        \
    for (int _nt = 0; _nt < 4; ++_nt)                                        \
      _Pragma("unroll")                                                      \
      for (int _mt = 0; _mt < 4; ++_mt)                                      \
        mfma3(acc[_mt][_nt], _ah[_mt], _al[_mt], FH[s][_nt], FL[s][_nt]);    \
} while (0)

#define WRITEBACK_ACC() do {                                                 \
    _Pragma("unroll")                                                        \
    for (int _mt = 0; _mt < 4; ++_mt)                                        \
      _Pragma("unroll")                                                      \
      for (int _nt = 0; _nt < 4; ++_nt)                                      \
        _Pragma("unroll")                                                    \
        for (int _r = 0; _r < 4; ++_r) {                                     \
            float _h = fmaxf(acc[_mt][_nt][_r], 0.f);                        \
            f16 _hi = (f16)_h;                                               \
            f16 _lo = (f16)(_h - (float)_hi);                                \
            int _row = 16*_mt + 4*q + _r;                                    \
            int _col = 64*cq + 16*_nt + lr;                                  \
            int _off = _row*256 + (((_col >> 3) ^ (_row & 31)) << 3) + (_col & 7); \
            hA_hi[_off] = _hi;                                               \
            hA_lo[_off] = _lo;                                               \
        }                                                                    \
} while (0)

#define INIT_ACC(brv) do {                                                   \
    _Pragma("unroll")                                                        \
    for (int _mt = 0; _mt < 4; ++_mt)                                        \
      _Pragma("unroll")                                                      \
      for (int _nt = 0; _nt < 4; ++_nt)                                      \
        acc[_mt][_nt] = (f32x4){(brv)[_nt], (brv)[_nt], (brv)[_nt], (brv)[_nt]}; \
} while (0)

#define OBS_WRITE() do {                                                     \
    float _o[32];                                                            \
    float _dx0 = px - 1.75f, _dy0 = py - 1.75f;                              \
    float _dx1 = px - 1.75f, _dy1 = py - 3.75f;                              \
    float _dx2 = px - 3.75f, _dy2 = py - 2.00f;                              \
    _o[0] = px*0.1f;        _o[1] = py*0.1f;                                 \
    _o[2] = (4.f-px)*0.1f;  _o[3] = (3.f-py)*0.1f;                           \
    _o[4] = -_dx0*0.1f;     _o[5] = -_dy0*0.1f;                              \
    _o[6] = -_dx1*0.1f;     _o[7] = -_dy1*0.1f;                              \
    _o[8] = -_dx2*0.1f;     _o[9] = -_dy2*0.1f;                              \
    _o[10] = sqrtf(_dx0*_dx0+_dy0*_dy0+1e-9f) - 0.38f;                       \
    _o[11] = sqrtf(_dx1*_dx1+_dy1*_dy1+1e-9f) - 0.42f;                       \
    _o[12] = sqrtf(_dx2*_dx2+_dy2*_dy2+1e-9f) - 0.34f;                       \
    _Pragma("unroll")                                                        \
    for (int _k = 13; _k < 32; ++_k) _o[_k] = 0.f;                           \
    _Pragma("unroll")                                                        \
    for (int _c = 0; _c < 4; ++_c) {                                         \
        f16x8 _hi, _lo;                                                      \
        _Pragma("unroll")                                                    \
        for (int _j = 0; _j < 8; ++_j) {                                     \
            float _v = _o[_c*8 + _j];                                        \
            f16 _h = (f16)_v;                                                \
            _hi[_j] = _h; _lo[_j] = (f16)(_v - (float)_h);                   \
        }                                                                    \
        *(f16x8*)(hA_hi + t*40 + _c*8) = _hi;                                \
        *(f16x8*)(hA_lo + t*40 + _c*8) = _lo;                                \
    }                                                                        \
} while (0)

__global__ __launch_bounds__(NT, 2)   // 2 waves/SIMD; live regs ~220 incl AGPR -> no spill
void rollout_kernel(const float* __restrict__ pos0, const float* __restrict__ wind,
                    const float* __restrict__ b1, const float* __restrict__ b2,
                    const float* __restrict__ b3, const float* __restrict__ wmu,
                    const float* __restrict__ bmu, const f16* __restrict__ wp,
                    float* __restrict__ out)
{
    // activations f16 hi/lo, XOR-chunk swizzle: (row,k)->row*256+((k>>3 ^ (row&31))<<3)+(k&7)
    __shared__ __align__(16) f16 hA_hi[M*256];   // 32 KB
    __shared__ __align__(16) f16 hA_lo[M*256];   // 32 KB -> 64 KB/block, 2 blocks/CU
    float* paL = (float*)(hA_hi + 8192);         // overlay in dead h2 rows 32..35

    const int t  = threadIdx.x;
    const int l  = t & 63;
    const int cq = t >> 6;         // wave id = col quarter: cols [64cq, 64cq+64)
    const int lr = l & 15;
    const int q  = l >> 4;

    float b1r[4], b2r[4], b3r[4], wmur[4][2];
    #pragma unroll
    for (int nt = 0; nt < 4; ++nt) {
        int col = 64*cq + 16*nt + lr;
        b1r[nt] = b1[col]; b2r[nt] = b2[col]; b3r[nt] = b3[col];
        wmur[nt][0] = wmu[2*col]; wmur[nt][1] = wmu[2*col + 1];
    }
    const float bm0 = bmu[0], bm1 = bmu[1];

    float px=0.f, py=0.f, wx=0.f, wy=0.f;
    float mx_s=-1e30f, sum_s=0.f, mx_r=-1e30f, sum_r=0.f;
    if (t < M) {
        int g = blockIdx.x*M + t;
        px = pos0[2*g]; py = pos0[2*g+1]; wx = wind[2*g]; wy = wind[2*g+1];
    }

    f16x8 FH[2][4], FL[2][4];   // packed B-frag ping-pong (2 chunks in flight)
    f32x4 acc[4][4];

    // ---- priming (steady-state slot map: slot0 = w2c0, slot1 = w1) ----
    FETCH_BP(W2H, W2L, 0, 0);
    FETCH_BP(W1H, W1L, 0, 1);
    if (t < M) { OBS_WRITE(); }

    for (int step = 0; step < HORIZON; ++step) {
        __syncthreads();   // B1: obs visible; paL consumed

        // ---- L1: obs(13 pad 32) x w1 (slot1) ----
        INIT_ACC(b1r);
        {
            f16x8 ah[4], al[4];
            #pragma unroll
            for (int mt = 0; mt < 4; ++mt) {
                int off = (16*mt + lr)*40 + q*8;
                ah[mt] = *(const f16x8*)(hA_hi + off);
                al[mt] = *(const f16x8*)(hA_lo + off);
            }
            #pragma unroll
            for (int nt = 0; nt < 4; ++nt)
              #pragma unroll
              for (int mt = 0; mt < 4; ++mt)
                mfma3(acc[mt][nt], ah[mt], al[mt], FH[1][nt], FL[1][nt]);
        }
        FETCH_BP(W2H, W2L, 1, 1);   // slot1 <- w2 c1 (after L1 consumed w1)
        __syncthreads();   // B2: obs reads done -> hA writable
        WRITEBACK_ACC();   // h1 -> hA
        INIT_ACC(b2r);
        __syncthreads();   // B3: h1 visible

        // ---- L2: 8 chunks, barrier-free; chunk c lives in slot c&1 ----
        #pragma unroll
        for (int g = 0; g < 8; ++g) {
            GEMM_CHUNK(g & 1, g);
            if (g < 6)       { FETCH_BP(W2H, W2L, g + 2, g & 1); }
            else if (g == 6) { FETCH_BP(W3H, W3L, 0, 0); }
            else             { FETCH_BP(W3H, W3L, 1, 1); }
        }
        __syncthreads();   // B4: h1 reads done
        WRITEBACK_ACC();   // h2 -> hA
        INIT_ACC(b3r);
        __syncthreads();   // B5: h2 visible

        // ---- L3: 8 chunks; tail refills next step's slot0=w2c0, slot1=w1 ----
        #pragma unroll
        for (int g = 0; g < 8; ++g) {
            GEMM_CHUNK(g & 1, g);
            if (g < 6)       { FETCH_BP(W3H, W3L, g + 2, g & 1); }
            else if (g == 6) { FETCH_BP(W2H, W2L, 0, 0); }
            else             { FETCH_BP(W1H, W1L, 0, 1); }
        }

        // ---- fused L4: partials from relu(acc=h3), registers + shuffles ----
        float pa[4][4][2];
        #pragma unroll
        for (int mt = 0; mt < 4; ++mt)
          #pragma unroll
          for (int r = 0; r < 4; ++r)
            { pa[mt][r][0] = 0.f; pa[mt][r][1] = 0.f; }
        #pragma unroll
        for (int mt = 0; mt < 4; ++mt)
          #pragma unroll
          for (int nt = 0; nt < 4; ++nt)
            #pragma unroll
            for (int r = 0; r < 4; ++r) {
                float h = fmaxf(acc[mt][nt][r], 0.f);
                pa[mt][r][0] = fmaf(h, wmur[nt][0], pa[mt][r][0]);
                pa[mt][r][1] = fmaf(h, wmur[nt][1], pa[mt][r][1]);
            }
        #pragma unroll
        for (int s = 0; s < 4; ++s)
            #pragma unroll
            for (int mt = 0; mt < 4; ++mt)
              #pragma unroll
              for (int r = 0; r < 4; ++r) {
                  pa[mt][r][0] += __shfl_xor(pa[mt][r][0], 1 << s, 64);
                  pa[mt][r][1] += __shfl_xor(pa[mt][r][1], 1 << s, 64);
              }
        __syncthreads();   // B6: all hA (h2) reads done -> paL region writable
        if (lr == 0) {
            #pragma unroll
            for (int mt = 0; mt < 4; ++mt)
              #pragma unroll
              for (int c = 0; c < 2; ++c) {
                  f32x4 v = {pa[mt][0][c], pa[mt][1][c], pa[mt][2][c], pa[mt][3][c]};
                  *(f32x4*)&paL[(cq*2 + c)*64 + 16*mt + 4*q] = v;
              }
        }
        __syncthreads();   // B7: paL visible

        // ---- P5 + P0: action, dynamics, STREL, next obs ----
        if (t < M) {
            float s0 = bm0 + paL[0*64 + t] + paL[2*64 + t] + paL[4*64 + t] + paL[6*64 + t];
            float s1 = bm1 + paL[1*64 + t] + paL[3*64 + t] + paL[5*64 + t] + paL[7*64 + t];
            float ax = fminf(fmaxf(s0, -1.f), 1.f);
            float ay = fminf(fmaxf(s1, -1.f), 1.f);
            float vx = 2.f*ax + wx, vy = 2.f*ay + wy;
            #pragma unroll
            for (int s = 0; s < 4; ++s) {
                px = fminf(fmaxf(px + 0.0625f*vx, -4.f), 10.f);
                py = fminf(fmaxf(py + 0.0625f*vy, -4.f), 10.f);
            }
            float dx0 = px - 1.75f, dy0 = py - 1.75f;
            float dx1 = px - 1.75f, dy1 = py - 3.75f;
            float dx2 = px - 3.75f, dy2 = py - 2.00f;
            float c0 = sqrtf(dx0*dx0+dy0*dy0+1e-9f) - 0.38f;
            float c1 = sqrtf(dx1*dx1+dy1*dy1+1e-9f) - 0.42f;
            float c2 = sqrtf(dx2*dx2+dy2*dy2+1e-9f) - 0.34f;
            float cmin = fminf(c0, fminf(c1, c2));
            float ssum = expf(-50.f*(c0-cmin)) + expf(-50.f*(c1-cmin)) + expf(-50.f*(c2-cmin));
            float safe = cmin - logf(ssum)/50.f;
            float gdx = px - 4.f, gdy = py - 3.f;
            float reach = 0.45f - sqrtf(gdx*gdx+gdy*gdy+1e-9f);
            float xs = -8.f*safe;
            if (xs > mx_s) { sum_s = sum_s*expf(mx_s - xs) + 1.f; mx_s = xs; }
            else           { sum_s += expf(xs - mx_s); }
            float xr = 8.f*reach;
            if (xr > mx_r) { sum_r = sum_r*expf(mx_r - xr) + 1.f; mx_r = xr; }
            else           { sum_r += expf(xr - mx_r); }
            OBS_WRITE();   // obs for next step
        }
    }

    if (t < M) {
        float rs = -(mx_s + logf(sum_s)) * 0.125f;
        float rr =  (mx_r + logf(sum_r)) * 0.125f;
        float u0 = -8.f*rs, u1 = -8.f*rr;
        float mu = fmaxf(u0, u1);
        float rho = -(mu + logf(expf(u0-mu) + expf(u1-mu))) * 0.125f;
        out[blockIdx.x*M + t] = rho;
    }
}

} // namespace

extern "C" void kernel_launch(void* const* d_in, const int* in_sizes, int n_in,
                              void* d_out, int out_size, void* d_ws, size_t ws_size,
                              hipStream_t stream)
{
    const float* pos0 = (const float*)d_in[0];
    const float* wind = (const float*)d_in[1];
    const float* w1   = (const float*)d_in[2];
    const float* b1   = (const float*)d_in[3];
    const float* w2   = (const float*)d_in[4];
    const float* b2   = (const float*)d_in[5];
    const float* w3   = (const float*)d_in[6];
    const float* b3   = (const float*)d_in[7];
    const float* wmu  = (const float*)d_in[8];
    const float* bmu  = (const float*)d_in[9];
    float* out = (float*)d_out;
    f16* wp = (f16*)d_ws;   // 278528 f16 = 544 KB packed weights

    prep_kernel<<<544, 256, 0, stream>>>(w1, w2, w3, wp);

    const int B = in_sizes[0] / 2;     // 32768 agents
    const int blocks = B / M;          // 512 blocks, 2/CU, single pass
    rollout_kernel<<<blocks, NT, 0, stream>>>(pos0, wind, b1, b2, b3,
                                              wmu, bmu, wp, out);
}

// Round 11
// 8999.318 us; speedup vs baseline: 1.0362x; 1.0362x over previous
//
#include <hip/hip_runtime.h>
#include <math.h>

typedef _Float16 f16;
typedef _Float16 f16x8 __attribute__((ext_vector_type(8)));
typedef float f32x4 __attribute__((ext_vector_type(4)));

namespace {

constexpr int NT = 512;     // 8 waves = 8 column-eighths; 2 waves/SIMD structurally
constexpr int M  = 128;     // agents per block -> 256 blocks -> 8.9 GB weight demand
constexpr int HORIZON = 64;

// packed f16 weight layout in d_ws (f16 units); per-chunk fragment order [q][col][j]
constexpr int W2H = 0;        // 65536 f16
constexpr int W2L = 65536;
constexpr int W3H = 131072;
constexpr int W3L = 196608;
constexpr int W1H = 262144;   // 8192 f16 (K padded 13->32)
constexpr int W1L = 270336;   // total 278528 f16 = 544 KB

// ---------------- weight pre-split + pre-pack (once per launch) ----------------
__global__ void prep_kernel(const float* __restrict__ w1, const float* __restrict__ w2,
                            const float* __restrict__ w3, f16* __restrict__ out)
{
    int tid = blockIdx.x * blockDim.x + threadIdx.x;   // 544*256 = 139264 exact
    float v; int hi, lo;
    if (tid < 65536) {          // w2
        int kc = tid >> 13, e2 = tid & 8191;
        int qq = e2 >> 11, col = (e2 >> 3) & 255, j = e2 & 7;
        v = w2[(kc*32 + qq*8 + j)*256 + col];
        hi = W2H + tid; lo = W2L + tid;
    } else if (tid < 131072) {  // w3
        int e = tid - 65536;
        int kc = e >> 13, e2 = e & 8191;
        int qq = e2 >> 11, col = (e2 >> 3) & 255, j = e2 & 7;
        v = w3[(kc*32 + qq*8 + j)*256 + col];
        hi = W3H + e; lo = W3L + e;
    } else {                    // w1, zero-padded to k=32
        int e = tid - 131072;
        int qq = e >> 11, col = (e >> 3) & 255, j = e & 7;
        int k = qq*8 + j;
        v = (k < 13) ? w1[k*256 + col] : 0.f;
        hi = W1H + e; lo = W1L + e;
    }
    f16 h = (f16)v;
    out[hi] = h;
    out[lo] = (f16)(v - (float)h);   // exact residual: 3-term MFMA = fp32-equiv
}

__device__ __forceinline__ void mfma3(f32x4& acc, f16x8 ah, f16x8 al, f16x8 bh, f16x8 bl)
{
    acc = __builtin_amdgcn_mfma_f32_16x16x32_f16(ah, bh, acc, 0, 0, 0);
    acc = __builtin_amdgcn_mfma_f32_16x16x32_f16(al, bh, acc, 0, 0, 0);
    acc = __builtin_amdgcn_mfma_f32_16x16x32_f16(ah, bl, acc, 0, 0, 0);
}

// load this wave's packed B-frags (hi+lo) for one 32-K chunk into slot s: 4x 16B loads
#define FETCH_BP(baseH, baseL, kc, s) do {                                   \
    _Pragma("unroll")                                                        \
    for (int _nt = 0; _nt < 2; ++_nt) {                                      \
        int _off = (kc)*8192 + (q*256 + 32*cw + 16*_nt + lr)*8;              \
        FH[s][_nt] = *(const f16x8*)(wp + (baseH) + _off);                   \
        FL[s][_nt] = *(const f16x8*)(wp + (baseL) + _off);                   \
    }                                                                        \
} while (0)

// one K-chunk: per-mt A-frags (8 live VGPRs), B straight from slot s
#define GEMM_CHUNK(s, kcl) do {                                              \
    _Pragma("unroll")                                                        \
    for (int _mt = 0; _mt < 8; ++_mt) {                                      \
        int _row = 16*_mt + lr;                                              \
        int _off = _row*256 + ((((kcl)*4 + q) ^ (_row & 31)) << 3);          \
        f16x8 _ah = *(const f16x8*)(hA_hi + _off);                           \
        f16x8 _al = *(const f16x8*)(hA_lo + _off);                           \
        _Pragma("unroll")                                                    \
        for (int _nt = 0; _nt < 2; ++_nt)                                    \
            mfma3(acc[_mt][_nt], _ah, _al, FH[s][_nt], FL[s][_nt]);          \
    }                                                                        \
} while (0)

#define WRITEBACK_ACC() do {                                                 \
    _Pragma("unroll")                                                        \
    for (int _mt = 0; _mt < 8; ++_mt)                                        \
      _Pragma("unroll")                                                      \
      for (int _nt = 0; _nt < 2; ++_nt)                                      \
        _Pragma("unroll")                                                    \
        for (int _r = 0; _r < 4; ++_r) {                                     \
            float _h = fmaxf(acc[_mt][_nt][_r], 0.f);                        \
            f16 _hi = (f16)_h;                                               \
            f16 _lo = (f16)(_h - (float)_hi);                                \
            int _row = 16*_mt + 4*q + _r;                                    \
            int _col = 32*cw + 16*_nt + lr;                                  \
            int _off = _row*256 + (((_col >> 3) ^ (_row & 31)) << 3) + (_col & 7); \
            hA_hi[_off] = _hi;                                               \
            hA_lo[_off] = _lo;                                               \
        }                                                                    \
} while (0)

#define INIT_ACC(brv) do {                                                   \
    _Pragma("unroll")                                                        \
    for (int _mt = 0; _mt < 8; ++_mt)                                        \
      _Pragma("unroll")                                                      \
      for (int _nt = 0; _nt < 2; ++_nt)                                      \
        acc[_mt][_nt] = (f32x4){(brv)[_nt], (brv)[_nt], (brv)[_nt], (brv)[_nt]}; \
} while (0)

#define OBS_WRITE() do {                                                     \
    float _o[32];                                                            \
    float _dx0 = px - 1.75f, _dy0 = py - 1.75f;                              \
    float _dx1 = px - 1.75f, _dy1 = py - 3.75f;                              \
    float _dx2 = px - 3.75f, _dy2 = py - 2.00f;                              \
    _o[0] = px*0.1f;        _o[1] = py*0.1f;                                 \
    _o[2] = (4.f-px)*0.1f;  _o[3] = (3.f-py)*0.1f;                           \
    _o[4] = -_dx0*0.1f;     _o[5] = -_dy0*0.1f;                              \
    _o[6] = -_dx1*0.1f;     _o[7] = -_dy1*0.1f;                              \
    _o[8] = -_dx2*0.1f;     _o[9] = -_dy2*0.1f;                              \
    _o[10] = sqrtf(_dx0*_dx0+_dy0*_dy0+1e-9f) - 0.38f;                       \
    _o[11] = sqrtf(_dx1*_dx1+_dy1*_dy1+1e-9f) - 0.42f;                       \
    _o[12] = sqrtf(_dx2*_dx2+_dy2*_dy2+1e-9f) - 0.34f;                       \
    _Pragma("unroll")                                                        \
    for (int _k = 13; _k < 32; ++_k) _o[_k] = 0.f;                           \
    _Pragma("unroll")                                                        \
    for (int _c = 0; _c < 4; ++_c) {                                         \
        f16x8 _hi, _lo;                                                      \
        _Pragma("unroll")                                                    \
        for (int _j = 0; _j < 8; ++_j) {                                     \
            float _v = _o[_c*8 + _j];                                        \
            f16 _h = (f16)_v;                                                \
            _hi[_j] = _h; _lo[_j] = (f16)(_v - (float)_h);                   \
        }                                                                    \
        *(f16x8*)(hA_hi + t*40 + _c*8) = _hi;                                \
        *(f16x8*)(hA_lo + t*40 + _c*8) = _lo;                                \
    }                                                                        \
} while (0)

__global__ __launch_bounds__(NT)   // NO min-waves arg: let the allocator pick the split
void rollout_kernel(const float* __restrict__ pos0, const float* __restrict__ wind,
                    const float* __restrict__ b1, const float* __restrict__ b2,
                    const float* __restrict__ b3, const float* __restrict__ wmu,
                    const float* __restrict__ bmu, const f16* __restrict__ wp,
                    float* __restrict__ out)
{
    // activations f16 hi/lo, XOR-chunk swizzle: (row,k)->row*256+((k>>3 ^ (row&31))<<3)+(k&7)
    __shared__ __align__(16) f16 hA_hi[M*256];   // 64 KB
    __shared__ __align__(16) f16 hA_lo[M*256];   // 64 KB -> 128 KB/block, 1 block/CU
    // L4 partials overlay: f16 idx 8192..12287 (rows 32..47), dead h2 between B6 and next L1 wb
    float* paL = (float*)(hA_hi + 8192);         // [8 cw][2 c][128 row] = 8 KB

    const int t  = threadIdx.x;
    const int l  = t & 63;
    const int cw = t >> 6;         // wave id = col eighth: cols [32cw, 32cw+32)
    const int lr = l & 15;
    const int q  = l >> 4;

    float b1r[2], b2r[2], b3r[2], wmur[2][2];
    #pragma unroll
    for (int nt = 0; nt < 2; ++nt) {
        int col = 32*cw + 16*nt + lr;
        b1r[nt] = b1[col]; b2r[nt] = b2[col]; b3r[nt] = b3[col];
        wmur[nt][0] = wmu[2*col]; wmur[nt][1] = wmu[2*col + 1];
    }
    const float bm0 = bmu[0], bm1 = bmu[1];

    float px=0.f, py=0.f, wx=0.f, wy=0.f;
    float mx_s=-1e30f, sum_s=0.f, mx_r=-1e30f, sum_r=0.f;
    if (t < M) {
        int g = blockIdx.x*M + t;
        px = pos0[2*g]; py = pos0[2*g+1]; wx = wind[2*g]; wy = wind[2*g+1];
    }

    f16x8 FH[2][2], FL[2][2];   // packed B-frag ping-pong: 32 VGPRs total
    f32x4 acc[8][2];            // 64 accumulator regs (AGPR-eligible)

    // ---- priming (steady-state slot map: slot0 = w2c0, slot1 = w1) ----
    FETCH_BP(W2H, W2L, 0, 0);
    FETCH_BP(W1H, W1L, 0, 1);
    if (t < M) { OBS_WRITE(); }

    for (int step = 0; step < HORIZON; ++step) {
        __syncthreads();   // B1: obs visible; paL consumed

        // ---- L1: obs(13 pad 32) x w1 (slot1) ----
        INIT_ACC(b1r);
        #pragma unroll
        for (int mt = 0; mt < 8; ++mt) {
            int off = (16*mt + lr)*40 + q*8;
            f16x8 ah = *(const f16x8*)(hA_hi + off);
            f16x8 al = *(const f16x8*)(hA_lo + off);
            #pragma unroll
            for (int nt = 0; nt < 2; ++nt)
                mfma3(acc[mt][nt], ah, al, FH[1][nt], FL[1][nt]);
        }
        FETCH_BP(W2H, W2L, 1, 1);   // slot1 <- w2 c1 (w1 consumed)
        __syncthreads();   // B2: obs reads done -> hA writable
        WRITEBACK_ACC();   // h1 -> hA
        INIT_ACC(b2r);
        __syncthreads();   // B3: h1 visible

        // ---- unified L2+L3: 16 chunks, barriers only at the h1->h2 switch ----
        #pragma unroll
        for (int g = 0; g < 16; ++g) {
            GEMM_CHUNK(g & 1, g & 7);
            if (g < 6)       { FETCH_BP(W2H, W2L, g + 2, g & 1); }
            else if (g == 6) { FETCH_BP(W3H, W3L, 0, 0); }
            else if (g == 7) { FETCH_BP(W3H, W3L, 1, 1); }
            else if (g < 14) { FETCH_BP(W3H, W3L, g - 6, g & 1); }
            else if (g == 14){ FETCH_BP(W2H, W2L, 0, 0); }     // next step w2c0
            else             { FETCH_BP(W1H, W1L, 0, 1); }     // next step w1
            if (g == 7) {
                __syncthreads();   // B4: h1 reads done
                WRITEBACK_ACC();   // h2 -> hA
                INIT_ACC(b3r);
                __syncthreads();   // B5: h2 visible
            }
        }

        // ---- fused L4: per-mt partials + 16-lane butterfly (8 live regs) ----
        {
            float paw[8][4][2];   // written via small per-mt lives, kept for stores
            #pragma unroll
            for (int mt = 0; mt < 8; ++mt) {
                float p0[4] = {0.f,0.f,0.f,0.f}, p1[4] = {0.f,0.f,0.f,0.f};
                #pragma unroll
                for (int nt = 0; nt < 2; ++nt)
                    #pragma unroll
                    for (int r = 0; r < 4; ++r) {
                        float h = fmaxf(acc[mt][nt][r], 0.f);
                        p0[r] = fmaf(h, wmur[nt][0], p0[r]);
                        p1[r] = fmaf(h, wmur[nt][1], p1[r]);
                    }
                #pragma unroll
                for (int s = 0; s < 4; ++s)
                    #pragma unroll
                    for (int r = 0; r < 4; ++r) {
                        p0[r] += __shfl_xor(p0[r], 1 << s, 64);
                        p1[r] += __shfl_xor(p1[r], 1 << s, 64);
                    }
                #pragma unroll
                for (int r = 0; r < 4; ++r) { paw[mt][r][0] = p0[r]; paw[mt][r][1] = p1[r]; }
            }
            __syncthreads();   // B6: all hA (h2) reads done -> paL region writable
            if (lr == 0) {
                #pragma unroll
                for (int mt = 0; mt < 8; ++mt)
                  #pragma unroll
                  for (int c = 0; c < 2; ++c) {
                      f32x4 v = {paw[mt][0][c], paw[mt][1][c], paw[mt][2][c], paw[mt][3][c]};
                      *(f32x4*)&paL[(cw*2 + c)*128 + 16*mt + 4*q] = v;
                  }
            }
        }
        __syncthreads();   // B7: paL visible

        // ---- P5 + P0: action, dynamics, STREL, next obs (threads 0..127) ----
        if (t < M) {
            float s0 = bm0, s1 = bm1;
            #pragma unroll
            for (int w = 0; w < 8; ++w) {
                s0 += paL[(w*2 + 0)*128 + t];
                s1 += paL[(w*2 + 1)*128 + t];
            }
            float ax = fminf(fmaxf(s0, -1.f), 1.f);
            float ay = fminf(fmaxf(s1, -1.f), 1.f);
            float vx = 2.f*ax + wx, vy = 2.f*ay + wy;
            #pragma unroll
            for (int s = 0; s < 4; ++s) {
                px = fminf(fmaxf(px + 0.0625f*vx, -4.f), 10.f);
                py = fminf(fmaxf(py + 0.0625f*vy, -4.f), 10.f);
            }
            float dx0 = px - 1.75f, dy0 = py - 1.75f;
            float dx1 = px - 1.75f, dy1 = py - 3.75f;
            float dx2 = px - 3.75f, dy2 = py - 2.00f;
            float c0 = sqrtf(dx0*dx0+dy0*dy0+1e-9f) - 0.38f;
            float c1 = sqrtf(dx1*dx1+dy1*dy1+1e-9f) - 0.42f;
            float c2 = sqrtf(dx2*dx2+dy2*dy2+1e-9f) - 0.34f;
            float cmin = fminf(c0, fminf(c1, c2));
            float ssum = expf(-50.f*(c0-cmin)) + expf(-50.f*(c1-cmin)) + expf(-50.f*(c2-cmin));
            float safe = cmin - logf(ssum)/50.f;
            float gdx = px - 4.f, gdy = py - 3.f;
            float reach = 0.45f - sqrtf(gdx*gdx+gdy*gdy+1e-9f);
            float xs = -8.f*safe;
            if (xs > mx_s) { sum_s = sum_s*expf(mx_s - xs) + 1.f; mx_s = xs; }
            else           { sum_s += expf(xs - mx_s); }
            float xr = 8.f*reach;
            if (xr > mx_r) { sum_r = sum_r*expf(mx_r - xr) + 1.f; mx_r = xr; }
            else           { sum_r += expf(xr - mx_r); }
            OBS_WRITE();   // obs for next step
        }
    }

    if (t < M) {
        float rs = -(mx_s + logf(sum_s)) * 0.125f;
        float rr =  (mx_r + logf(sum_r)) * 0.125f;
        float u0 = -8.f*rs, u1 = -8.f*rr;
        float mu = fmaxf(u0, u1);
        float rho = -(mu + logf(expf(u0-mu) + expf(u1-mu))) * 0.125f;
        out[blockIdx.x*M + t] = rho;
    }
}

} // namespace

extern "C" void kernel_launch(void* const* d_in, const int* in_sizes, int n_in,
                              void* d_out, int out_size, void* d_ws, size_t ws_size,
                              hipStream_t stream)
{
    const float* pos0 = (const float*)d_in[0];
    const float* wind = (const float*)d_in[1];
    const float* w1   = (const float*)d_in[2];
    const float* b1   = (const float*)d_in[3];
    const float* w2   = (const float*)d_in[4];
    const float* b2   = (const float*)d_in[5];
    const float* w3   = (const float*)d_in[6];
    const float* b3   = (const float*)d_in[7];
    const float* wmu  = (const float*)d_in[8];
    const float* bmu  = (const float*)d_in[9];
    float* out = (float*)d_out;
    f16* wp = (f16*)d_ws;   // 278528 f16 = 544 KB packed weights

    prep_kernel<<<544, 256, 0, stream>>>(w1, w2, w3, wp);

    const int B = in_sizes[0] / 2;     // 32768 agents
    const int blocks = B / M;          // 256 blocks, 1/CU, single pass
    rollout_kernel<<<blocks, NT, 0, stream>>>(pos0, wind, b1, b2, b3,
                                              wmu, bmu, wp, out);
}

// Round 12
// 3568.343 us; speedup vs baseline: 2.6134x; 2.5220x over previous
//
#include <hip/hip_runtime.h>
#include <math.h>

typedef _Float16 f16;
typedef _Float16 f16x8 __attribute__((ext_vector_type(8)));
typedef float f32x4 __attribute__((ext_vector_type(4)));

namespace {

constexpr int NT = 512;     // 8 waves = 8 column-eighths; 2 blocks/CU (68 KB LDS)
constexpr int M  = 64;      // agents per block
constexpr int HORIZON = 64;

// packed f16 weight layout in d_ws (f16 units); per-chunk fragment order [q][col][j]
constexpr int W2H = 0;        // 65536 f16
constexpr int W2L = 65536;
constexpr int W3H = 131072;
constexpr int W3L = 196608;
constexpr int W1H = 262144;   // 8192 f16 (K padded 13->32)
constexpr int W1L = 270336;   // total 278528 f16 = 544 KB

// ---------------- weight pre-split + pre-pack (once per launch) ----------------
__global__ void prep_kernel(const float* __restrict__ w1, const float* __restrict__ w2,
                            const float* __restrict__ w3, f16* __restrict__ out)
{
    int tid = blockIdx.x * blockDim.x + threadIdx.x;   // 544*256 = 139264 exact
    float v; int hi, lo;
    if (tid < 65536) {          // w2
        int kc = tid >> 13, e2 = tid & 8191;
        int qq = e2 >> 11, col = (e2 >> 3) & 255, j = e2 & 7;
        v = w2[(kc*32 + qq*8 + j)*256 + col];
        hi = W2H + tid; lo = W2L + tid;
    } else if (tid < 131072) {  // w3
        int e = tid - 65536;
        int kc = e >> 13, e2 = e & 8191;
        int qq = e2 >> 11, col = (e2 >> 3) & 255, j = e2 & 7;
        v = w3[(kc*32 + qq*8 + j)*256 + col];
        hi = W3H + e; lo = W3L + e;
    } else {                    // w1, zero-padded to k=32
        int e = tid - 131072;
        int qq = e >> 11, col = (e >> 3) & 255, j = e & 7;
        int k = qq*8 + j;
        v = (k < 13) ? w1[k*256 + col] : 0.f;
        hi = W1H + e; lo = W1L + e;
    }
    f16 h = (f16)v;
    out[hi] = h;
    out[lo] = (f16)(v - (float)h);   // exact residual: 3-term MFMA = fp32-equiv
}

__device__ __forceinline__ void mfma3(f32x4& acc, f16x8 ah, f16x8 al, f16x8 bh, f16x8 bl)
{
    acc = __builtin_amdgcn_mfma_f32_16x16x32_f16(ah, bh, acc, 0, 0, 0);
    acc = __builtin_amdgcn_mfma_f32_16x16x32_f16(al, bh, acc, 0, 0, 0);
    acc = __builtin_amdgcn_mfma_f32_16x16x32_f16(ah, bl, acc, 0, 0, 0);
}

// load this wave's packed B-frags (hi+lo) for one 32-K chunk into slot s: 4x 16B loads
#define FETCH_BP(baseH, baseL, kc, s) do {                                   \
    _Pragma("unroll")                                                        \
    for (int _nt = 0; _nt < 2; ++_nt) {                                      \
        int _off = (kc)*8192 + (q*256 + 32*cw + 16*_nt + lr)*8;              \
        FH[s][_nt] = *(const f16x8*)(wp + (baseH) + _off);                   \
        FL[s][_nt] = *(const f16x8*)(wp + (baseL) + _off);                   \
    }                                                                        \
} while (0)

// one K-chunk: per-mt transient A-frags, B straight from slot s; 24 MFMA
#define GEMM_CHUNK(s, kcl) do {                                              \
    _Pragma("unroll")                                                        \
    for (int _mt = 0; _mt < 4; ++_mt) {                                      \
        int _row = 16*_mt + lr;                                              \
        int _off = _row*256 + ((((kcl)*4 + q) ^ (_row & 31)) << 3);          \
        f16x8 _ah = *(const f16x8*)(hA_hi + _off);                           \
        f16x8 _al = *(const f16x8*)(hA_lo + _off);                           \
        _Pragma("unroll")                                                    \
        for (int _nt = 0; _nt < 2; ++_nt)                                    \
            mfma3(acc[_mt][_nt], _ah, _al, FH[s][_nt], FL[s][_nt]);          \
    }                                                                        \
} while (0)

#define WRITEBACK_ACC() do {                                                 \
    _Pragma("unroll")                                                        \
    for (int _mt = 0; _mt < 4; ++_mt)                                        \
      _Pragma("unroll")                                                      \
      for (int _nt = 0; _nt < 2; ++_nt)                                      \
        _Pragma("unroll")                                                    \
        for (int _r = 0; _r < 4; ++_r) {                                     \
            float _h = fmaxf(acc[_mt][_nt][_r], 0.f);                        \
            f16 _hi = (f16)_h;                                               \
            f16 _lo = (f16)(_h - (float)_hi);                                \
            int _row = 16*_mt + 4*q + _r;                                    \
            int _col = 32*cw + 16*_nt + lr;                                  \
            int _off = _row*256 + (((_col >> 3) ^ (_row & 31)) << 3) + (_col & 7); \
            hA_hi[_off] = _hi;                                               \
            hA_lo[_off] = _lo;                                               \
        }                                                                    \
} while (0)

#define INIT_ACC(brv) do {                                                   \
    _Pragma("unroll")                                                        \
    for (int _mt = 0; _mt < 4; ++_mt)                                        \
      _Pragma("unroll")                                                      \
      for (int _nt = 0; _nt < 2; ++_nt)                                      \
        acc[_mt][_nt] = (f32x4){(brv)[_nt], (brv)[_nt], (brv)[_nt], (brv)[_nt]}; \
} while (0)

#define OBS_WRITE() do {                                                     \
    float _o[32];                                                            \
    float _dx0 = px - 1.75f, _dy0 = py - 1.75f;                              \
    float _dx1 = px - 1.75f, _dy1 = py - 3.75f;                              \
    float _dx2 = px - 3.75f, _dy2 = py - 2.00f;                              \
    _o[0] = px*0.1f;        _o[1] = py*0.1f;                                 \
    _o[2] = (4.f-px)*0.1f;  _o[3] = (3.f-py)*0.1f;                           \
    _o[4] = -_dx0*0.1f;     _o[5] = -_dy0*0.1f;                              \
    _o[6] = -_dx1*0.1f;     _o[7] = -_dy1*0.1f;                              \
    _o[8] = -_dx2*0.1f;     _o[9] = -_dy2*0.1f;                              \
    _o[10] = sqrtf(_dx0*_dx0+_dy0*_dy0+1e-9f) - 0.38f;                       \
    _o[11] = sqrtf(_dx1*_dx1+_dy1*_dy1+1e-9f) - 0.42f;                       \
    _o[12] = sqrtf(_dx2*_dx2+_dy2*_dy2+1e-9f) - 0.34f;                       \
    _Pragma("unroll")                                                        \
    for (int _k = 13; _k < 32; ++_k) _o[_k] = 0.f;                           \
    _Pragma("unroll")                                                        \
    for (int _c = 0; _c < 4; ++_c) {                                         \
        f16x8 _hi, _lo;                                                      \
        _Pragma("unroll")                                                    \
        for (int _j = 0; _j < 8; ++_j) {                                     \
            float _v = _o[_c*8 + _j];                                        \
            f16 _h = (f16)_v;                                                \
            _hi[_j] = _h; _lo[_j] = (f16)(_v - (float)_h);                   \
        }                                                                    \
        *(f16x8*)(hA_hi + t*40 + _c*8) = _hi;                                \
        *(f16x8*)(hA_lo + t*40 + _c*8) = _lo;                                \
    }                                                                        \
} while (0)

__global__ __launch_bounds__(NT)
void rollout_kernel(const float* __restrict__ pos0, const float* __restrict__ wind,
                    const float* __restrict__ b1, const float* __restrict__ b2,
                    const float* __restrict__ b3, const float* __restrict__ wmu,
                    const float* __restrict__ bmu, const f16* __restrict__ wp,
                    float* __restrict__ out)
{
    // activations f16 hi/lo, XOR-chunk swizzle: (row,k)->row*256+((k>>3 ^ (row&31))<<3)+(k&7)
    __shared__ __align__(16) f16 hA_hi[M*256];   // 32 KB
    __shared__ __align__(16) f16 hA_lo[M*256];   // 32 KB
    __shared__ __align__(16) float paL[16*M];    // 4 KB separate (no overlay, no reg hold)
    // total 68 KB -> 2 blocks/CU, 16 waves/CU

    const int t  = threadIdx.x;
    const int l  = t & 63;
    const int cw = t >> 6;         // wave id = col eighth: cols [32cw, 32cw+32)
    const int lr = l & 15;
    const int q  = l >> 4;

    float b1r[2], b2r[2], b3r[2], wmur[2][2];
    #pragma unroll
    for (int nt = 0; nt < 2; ++nt) {
        int col = 32*cw + 16*nt + lr;
        b1r[nt] = b1[col]; b2r[nt] = b2[col]; b3r[nt] = b3[col];
        wmur[nt][0] = wmu[2*col]; wmur[nt][1] = wmu[2*col + 1];
    }
    const float bm0 = bmu[0], bm1 = bmu[1];

    float px=0.f, py=0.f, wx=0.f, wy=0.f;
    float mx_s=-1e30f, sum_s=0.f, mx_r=-1e30f, sum_r=0.f;
    if (t < M) {
        int g = blockIdx.x*M + t;
        px = pos0[2*g]; py = pos0[2*g+1]; wx = wind[2*g]; wy = wind[2*g+1];
    }

    f16x8 FH[2][2], FL[2][2];   // packed B-frag ping-pong: 32 VGPRs
    f32x4 acc[4][2];            // 32 accumulator regs

    // ---- priming (steady-state slot map: slot0 = w2c0, slot1 = w1) ----
    FETCH_BP(W2H, W2L, 0, 0);
    FETCH_BP(W1H, W1L, 0, 1);
    if (t < M) { OBS_WRITE(); }

    for (int step = 0; step < HORIZON; ++step) {
        __syncthreads();   // B1: obs visible

        // ---- L1: obs(13 pad 32) x w1 (slot1) ----
        INIT_ACC(b1r);
        #pragma unroll
        for (int mt = 0; mt < 4; ++mt) {
            int off = (16*mt + lr)*40 + q*8;
            f16x8 ah = *(const f16x8*)(hA_hi + off);
            f16x8 al = *(const f16x8*)(hA_lo + off);
            #pragma unroll
            for (int nt = 0; nt < 2; ++nt)
                mfma3(acc[mt][nt], ah, al, FH[1][nt], FL[1][nt]);
        }
        FETCH_BP(W2H, W2L, 1, 1);   // slot1 <- w2 c1 (w1 consumed)
        __syncthreads();   // B2: obs reads done -> hA writable
        WRITEBACK_ACC();   // h1 -> hA
        INIT_ACC(b2r);
        __syncthreads();   // B3: h1 visible

        // ---- unified L2+L3: 16 chunks; barriers only at the h1->h2 switch ----
        #pragma unroll
        for (int g = 0; g < 16; ++g) {
            GEMM_CHUNK(g & 1, g & 7);
            if (g < 6)       { FETCH_BP(W2H, W2L, g + 2, g & 1); }
            else if (g == 6) { FETCH_BP(W3H, W3L, 0, 0); }
            else if (g == 7) { FETCH_BP(W3H, W3L, 1, 1); }
            else if (g < 14) { FETCH_BP(W3H, W3L, g - 6, g & 1); }
            else if (g == 14){ FETCH_BP(W2H, W2L, 0, 0); }     // next step w2c0
            else             { FETCH_BP(W1H, W1L, 0, 1); }     // next step w1
            if (g == 7) {
                __syncthreads();   // B4: h1 reads done
                WRITEBACK_ACC();   // h2 -> hA
                INIT_ACC(b3r);
                __syncthreads();   // B5: h2 visible
            }
        }

        // ---- fused L4: per-mt transient partials -> immediate paL store ----
        #pragma unroll
        for (int mt = 0; mt < 4; ++mt) {
            float p0[4] = {0.f,0.f,0.f,0.f}, p1[4] = {0.f,0.f,0.f,0.f};
            #pragma unroll
            for (int nt = 0; nt < 2; ++nt)
                #pragma unroll
                for (int r = 0; r < 4; ++r) {
                    float h = fmaxf(acc[mt][nt][r], 0.f);
                    p0[r] = fmaf(h, wmur[nt][0], p0[r]);
                    p1[r] = fmaf(h, wmur[nt][1], p1[r]);
                }
            #pragma unroll
            for (int s = 0; s < 4; ++s)
                #pragma unroll
                for (int r = 0; r < 4; ++r) {
                    p0[r] += __shfl_xor(p0[r], 1 << s, 64);
                    p1[r] += __shfl_xor(p1[r], 1 << s, 64);
                }
            if (lr == 0) {   // paL is a separate array: store NOW, no reg hold
                f32x4 v0 = {p0[0], p0[1], p0[2], p0[3]};
                f32x4 v1 = {p1[0], p1[1], p1[2], p1[3]};
                *(f32x4*)&paL[(cw*2 + 0)*M + 16*mt + 4*q] = v0;
                *(f32x4*)&paL[(cw*2 + 1)*M + 16*mt + 4*q] = v1;
            }
        }
        __syncthreads();   // B6: paL visible; all hA reads (L3) done

        // ---- P5 + P0: action, dynamics, STREL, next obs (threads 0..63) ----
        if (t < M) {
            float s0 = bm0, s1 = bm1;
            #pragma unroll
            for (int w = 0; w < 8; ++w) {
                s0 += paL[(w*2 + 0)*M + t];
                s1 += paL[(w*2 + 1)*M + t];
            }
            float ax = fminf(fmaxf(s0, -1.f), 1.f);
            float ay = fminf(fmaxf(s1, -1.f), 1.f);
            float vx = 2.f*ax + wx, vy = 2.f*ay + wy;
            #pragma unroll
            for (int s = 0; s < 4; ++s) {
                px = fminf(fmaxf(px + 0.0625f*vx, -4.f), 10.f);
                py = fminf(fmaxf(py + 0.0625f*vy, -4.f), 10.f);
            }
            float dx0 = px - 1.75f, dy0 = py - 1.75f;
            float dx1 = px - 1.75f, dy1 = py - 3.75f;
            float dx2 = px - 3.75f, dy2 = py - 2.00f;
            float c0 = sqrtf(dx0*dx0+dy0*dy0+1e-9f) - 0.38f;
            float c1 = sqrtf(dx1*dx1+dy1*dy1+1e-9f) - 0.42f;
            float c2 = sqrtf(dx2*dx2+dy2*dy2+1e-9f) - 0.34f;
            float cmin = fminf(c0, fminf(c1, c2));
            float ssum = expf(-50.f*(c0-cmin)) + expf(-50.f*(c1-cmin)) + expf(-50.f*(c2-cmin));
            float safe = cmin - logf(ssum)/50.f;
            float gdx = px - 4.f, gdy = py - 3.f;
            float reach = 0.45f - sqrtf(gdx*gdx+gdy*gdy+1e-9f);
            float xs = -8.f*safe;
            if (xs > mx_s) { sum_s = sum_s*expf(mx_s - xs) + 1.f; mx_s = xs; }
            else           { sum_s += expf(xs - mx_s); }
            float xr = 8.f*reach;
            if (xr > mx_r) { sum_r = sum_r*expf(mx_r - xr) + 1.f; mx_r = xr; }
            else           { sum_r += expf(xr - mx_r); }
            OBS_WRITE();   // obs for next step
        }
    }

    if (t < M) {
        float rs = -(mx_s + logf(sum_s)) * 0.125f;
        float rr =  (mx_r + logf(sum_r)) * 0.125f;
        float u0 = -8.f*rs, u1 = -8.f*rr;
        float mu = fmaxf(u0, u1);
        float rho = -(mu + logf(expf(u0-mu) + expf(u1-mu))) * 0.125f;
        out[blockIdx.x*M + t] = rho;
    }
}

} // namespace

extern "C" void kernel_launch(void* const* d_in, const int* in_sizes, int n_in,
                              void* d_out, int out_size, void* d_ws, size_t ws_size,
                              hipStream_t stream)
{
    const float* pos0 = (const float*)d_in[0];
    const float* wind = (const float*)d_in[1];
    const float* w1   = (const float*)d_in[2];
    const float* b1   = (const float*)d_in[3];
    const float* w2   = (const float*)d_in[4];
    const float* b2   = (const float*)d_in[5];
    const float* w3   = (const float*)d_in[6];
    const float* b3   = (const float*)d_in[7];
    const float* wmu  = (const float*)d_in[8];
    const float* bmu  = (const float*)d_in[9];
    float* out = (float*)d_out;
    f16* wp = (f16*)d_ws;   // 278528 f16 = 544 KB packed weights

    prep_kernel<<<544, 256, 0, stream>>>(w1, w2, w3, wp);

    const int B = in_sizes[0] / 2;     // 32768 agents
    const int blocks = B / M;          // 512 blocks, 2/CU, single pass
    rollout_kernel<<<blocks, NT, 0, stream>>>(pos0, wind, b1, b2, b3,
                                              wmu, bmu, wp, out);
}

// Round 13
// 3536.282 us; speedup vs baseline: 2.6371x; 1.0091x over previous
//
#include <hip/hip_runtime.h>
#include <math.h>

typedef _Float16 f16;
typedef _Float16 f16x8 __attribute__((ext_vector_type(8)));
typedef float f32x4 __attribute__((ext_vector_type(4)));

namespace {

constexpr int NT = 256;     // 4 waves = 4 column-quarters; 2 blocks/CU (66 KB LDS)
constexpr int M  = 64;      // agents per block
constexpr int HORIZON = 64;

// packed f16 weight layout in d_ws (f16 units); per-chunk fragment order [q][col][j]
constexpr int W2H = 0;        // 65536 f16
constexpr int W2L = 65536;
constexpr int W3H = 131072;
constexpr int W3L = 196608;
constexpr int W1H = 262144;   // 8192 f16 (K padded 13->32)
constexpr int W1L = 270336;   // total 278528 f16 = 544 KB

// ---------------- weight pre-split + pre-pack (once per launch) ----------------
__global__ void prep_kernel(const float* __restrict__ w1, const float* __restrict__ w2,
                            const float* __restrict__ w3, f16* __restrict__ out)
{
    int tid = blockIdx.x * blockDim.x + threadIdx.x;   // 544*256 = 139264 exact
    float v; int hi, lo;
    if (tid < 65536) {          // w2
        int kc = tid >> 13, e2 = tid & 8191;
        int qq = e2 >> 11, col = (e2 >> 3) & 255, j = e2 & 7;
        v = w2[(kc*32 + qq*8 + j)*256 + col];
        hi = W2H + tid; lo = W2L + tid;
    } else if (tid < 131072) {  // w3
        int e = tid - 65536;
        int kc = e >> 13, e2 = e & 8191;
        int qq = e2 >> 11, col = (e2 >> 3) & 255, j = e2 & 7;
        v = w3[(kc*32 + qq*8 + j)*256 + col];
        hi = W3H + e; lo = W3L + e;
    } else {                    // w1, zero-padded to k=32
        int e = tid - 131072;
        int qq = e >> 11, col = (e >> 3) & 255, j = e & 7;
        int k = qq*8 + j;
        v = (k < 13) ? w1[k*256 + col] : 0.f;
        hi = W1H + e; lo = W1L + e;
    }
    f16 h = (f16)v;
    out[hi] = h;
    out[lo] = (f16)(v - (float)h);   // exact residual: 3-term MFMA = fp32-equiv
}

__device__ __forceinline__ void mfma3(f32x4& acc, f16x8 ah, f16x8 al, f16x8 bh, f16x8 bl)
{
    acc = __builtin_amdgcn_mfma_f32_16x16x32_f16(ah, bh, acc, 0, 0, 0);
    acc = __builtin_amdgcn_mfma_f32_16x16x32_f16(al, bh, acc, 0, 0, 0);
    acc = __builtin_amdgcn_mfma_f32_16x16x32_f16(ah, bl, acc, 0, 0, 0);
}

// load this wave's packed B-frags (hi+lo) for one 32-K chunk into slot s: 8x 16B loads
#define FETCH_BP(baseH, baseL, kc, s) do {                                   \
    _Pragma("unroll")                                                        \
    for (int _nt = 0; _nt < 4; ++_nt) {                                      \
        int _off = (kc)*8192 + (q*256 + 64*cq + 16*_nt + lr)*8;              \
        FH[s][_nt] = *(const f16x8*)(wp + (baseH) + _off);                   \
        FL[s][_nt] = *(const f16x8*)(wp + (baseL) + _off);                   \
    }                                                                        \
} while (0)

// one K-chunk: per-mt transient A-frags, B straight from slot s; 48 MFMA
#define GEMM_CHUNK(s, kcl) do {                                              \
    _Pragma("unroll")                                                        \
    for (int _mt = 0; _mt < 4; ++_mt) {                                      \
        int _row = 16*_mt + lr;                                              \
        int _off = _row*256 + ((((kcl)*4 + q) ^ (_row & 31)) << 3);          \
        f16x8 _ah = *(const f16x8*)(hA_hi + _off);                           \
        f16x8 _al = *(const f16x8*)(hA_lo + _off);                           \
        _Pragma("unroll")                                                    \
        for (int _nt = 0; _nt < 4; ++_nt)                                    \
            mfma3(acc[_mt][_nt], _ah, _al, FH[s][_nt], FL[s][_nt]);          \
    }                                                                        \
} while (0)

#define WRITEBACK_ACC() do {                                                 \
    _Pragma("unroll")                                                        \
    for (int _mt = 0; _mt < 4; ++_mt)                                        \
      _Pragma("unroll")                                                      \
      for (int _nt = 0; _nt < 4; ++_nt)                                      \
        _Pragma("unroll")                                                    \
        for (int _r = 0; _r < 4; ++_r) {                                     \
            float _h = fmaxf(acc[_mt][_nt][_r], 0.f);                        \
            f16 _hi = (f16)_h;                                               \
            f16 _lo = (f16)(_h - (float)_hi);                                \
            int _row = 16*_mt + 4*q + _r;                                    \
            int _col = 64*cq + 16*_nt + lr;                                  \
            int _off = _row*256 + (((_col >> 3) ^ (_row & 31)) << 3) + (_col & 7); \
            hA_hi[_off] = _hi;                                               \
            hA_lo[_off] = _lo;                                               \
        }                                                                    \
} while (0)

#define INIT_ACC(brv) do {                                                   \
    _Pragma("unroll")                                                        \
    for (int _mt = 0; _mt < 4; ++_mt)                                        \
      _Pragma("unroll")                                                      \
      for (int _nt = 0; _nt < 4; ++_nt)                                      \
        acc[_mt][_nt] = (f32x4){(brv)[_nt], (brv)[_nt], (brv)[_nt], (brv)[_nt]}; \
} while (0)

#define OBS_WRITE() do {                                                     \
    float _o[32];                                                            \
    float _dx0 = px - 1.75f, _dy0 = py - 1.75f;                              \
    float _dx1 = px - 1.75f, _dy1 = py - 3.75f;                              \
    float _dx2 = px - 3.75f, _dy2 = py - 2.00f;                              \
    _o[0] = px*0.1f;        _o[1] = py*0.1f;                                 \
    _o[2] = (4.f-px)*0.1f;  _o[3] = (3.f-py)*0.1f;                           \
    _o[4] = -_dx0*0.1f;     _o[5] = -_dy0*0.1f;                              \
    _o[6] = -_dx1*0.1f;     _o[7] = -_dy1*0.1f;                              \
    _o[8] = -_dx2*0.1f;     _o[9] = -_dy2*0.1f;                              \
    _o[10] = sqrtf(_dx0*_dx0+_dy0*_dy0+1e-9f) - 0.38f;                       \
    _o[11] = sqrtf(_dx1*_dx1+_dy1*_dy1+1e-9f) - 0.42f;                       \
    _o[12] = sqrtf(_dx2*_dx2+_dy2*_dy2+1e-9f) - 0.34f;                       \
    _Pragma("unroll")                                                        \
    for (int _k = 13; _k < 32; ++_k) _o[_k] = 0.f;                           \
    _Pragma("unroll")                                                        \
    for (int _c = 0; _c < 4; ++_c) {                                         \
        f16x8 _hi, _lo;                                                      \
        _Pragma("unroll")                                                    \
        for (int _j = 0; _j < 8; ++_j) {                                     \
            float _v = _o[_c*8 + _j];                                        \
            f16 _h = (f16)_v;                                                \
            _hi[_j] = _h; _lo[_j] = (f16)(_v - (float)_h);                   \
        }                                                                    \
        *(f16x8*)(hA_hi + t*40 + _c*8) = _hi;                                \
        *(f16x8*)(hA_lo + t*40 + _c*8) = _lo;                                \
    }                                                                        \
} while (0)

__global__ __launch_bounds__(NT, 1)   // 1 wave/EU floor -> allocator may use full 256 arch VGPRs
void rollout_kernel(const float* __restrict__ pos0, const float* __restrict__ wind,
                    const float* __restrict__ b1, const float* __restrict__ b2,
                    const float* __restrict__ b3, const float* __restrict__ wmu,
                    const float* __restrict__ bmu, const f16* __restrict__ wp,
                    float* __restrict__ out)
{
    // activations f16 hi/lo, XOR-chunk swizzle: (row,k)->row*256+((k>>3 ^ (row&31))<<3)+(k&7)
    __shared__ __align__(16) f16 hA_hi[M*256];   // 32 KB
    __shared__ __align__(16) f16 hA_lo[M*256];   // 32 KB
    __shared__ __align__(16) float paL[8*M];     // 2 KB separate -> 66 KB total, 2 blocks/CU

    const int t  = threadIdx.x;
    const int l  = t & 63;
    const int cq = t >> 6;         // wave id = col quarter: cols [64cq, 64cq+64)
    const int lr = l & 15;
    const int q  = l >> 4;

    float b1r[4], b2r[4], b3r[4], wmur[4][2];
    #pragma unroll
    for (int nt = 0; nt < 4; ++nt) {
        int col = 64*cq + 16*nt + lr;
        b1r[nt] = b1[col]; b2r[nt] = b2[col]; b3r[nt] = b3[col];
        wmur[nt][0] = wmu[2*col]; wmur[nt][1] = wmu[2*col + 1];
    }
    const float bm0 = bmu[0], bm1 = bmu[1];

    float px=0.f, py=0.f, wx=0.f, wy=0.f;
    float mx_s=-1e30f, sum_s=0.f, mx_r=-1e30f, sum_r=0.f;
    if (t < M) {
        int g = blockIdx.x*M + t;
        px = pos0[2*g]; py = pos0[2*g+1]; wx = wind[2*g]; wy = wind[2*g+1];
    }

    f16x8 FH[2][4], FL[2][4];   // packed B-frag ping-pong: 64 VGPRs
    f32x4 acc[4][4];            // 64 accumulator regs (AGPR-eligible)

    // ---- priming (steady-state slot map: slot0 = w2c0, slot1 = w1) ----
    FETCH_BP(W2H, W2L, 0, 0);
    FETCH_BP(W1H, W1L, 0, 1);
    if (t < M) { OBS_WRITE(); }

    for (int step = 0; step < HORIZON; ++step) {
        __syncthreads();   // B1: obs visible

        // ---- L1: obs(13 pad 32) x w1 (slot1) ----
        INIT_ACC(b1r);
        #pragma unroll
        for (int mt = 0; mt < 4; ++mt) {
            int off = (16*mt + lr)*40 + q*8;
            f16x8 ah = *(const f16x8*)(hA_hi + off);
            f16x8 al = *(const f16x8*)(hA_lo + off);
            #pragma unroll
            for (int nt = 0; nt < 4; ++nt)
                mfma3(acc[mt][nt], ah, al, FH[1][nt], FL[1][nt]);
        }
        FETCH_BP(W2H, W2L, 1, 1);   // slot1 <- w2 c1 (w1 consumed)
        __syncthreads();   // B2: obs reads done -> hA writable
        WRITEBACK_ACC();   // h1 -> hA
        INIT_ACC(b2r);
        __syncthreads();   // B3: h1 visible

        // ---- unified L2+L3: 16 chunks; barriers only at the h1->h2 switch ----
        #pragma unroll
        for (int g = 0; g < 16; ++g) {
            GEMM_CHUNK(g & 1, g & 7);
            if (g < 6)       { FETCH_BP(W2H, W2L, g + 2, g & 1); }
            else if (g == 6) { FETCH_BP(W3H, W3L, 0, 0); }
            else if (g == 7) { FETCH_BP(W3H, W3L, 1, 1); }
            else if (g < 14) { FETCH_BP(W3H, W3L, g - 6, g & 1); }
            else if (g == 14){ FETCH_BP(W2H, W2L, 0, 0); }     // next step w2c0
            else             { FETCH_BP(W1H, W1L, 0, 1); }     // next step w1
            if (g == 7) {
                __syncthreads();   // B4: h1 reads done
                WRITEBACK_ACC();   // h2 -> hA
                INIT_ACC(b3r);
                __syncthreads();   // B5: h2 visible
            }
        }

        // ---- fused L4: per-mt transient partials -> immediate paL store ----
        #pragma unroll
        for (int mt = 0; mt < 4; ++mt) {
            float p0[4] = {0.f,0.f,0.f,0.f}, p1[4] = {0.f,0.f,0.f,0.f};
            #pragma unroll
            for (int nt = 0; nt < 4; ++nt)
                #pragma unroll
                for (int r = 0; r < 4; ++r) {
                    float h = fmaxf(acc[mt][nt][r], 0.f);
                    p0[r] = fmaf(h, wmur[nt][0], p0[r]);
                    p1[r] = fmaf(h, wmur[nt][1], p1[r]);
                }
            #pragma unroll
            for (int s = 0; s < 4; ++s)
                #pragma unroll
                for (int r = 0; r < 4; ++r) {
                    p0[r] += __shfl_xor(p0[r], 1 << s, 64);
                    p1[r] += __shfl_xor(p1[r], 1 << s, 64);
                }
            if (lr == 0) {   // paL separate: store immediately, no reg hold
                f32x4 v0 = {p0[0], p0[1], p0[2], p0[3]};
                f32x4 v1 = {p1[0], p1[1], p1[2], p1[3]};
                *(f32x4*)&paL[(cq*2 + 0)*M + 16*mt + 4*q] = v0;
                *(f32x4*)&paL[(cq*2 + 1)*M + 16*mt + 4*q] = v1;
            }
        }
        __syncthreads();   // B6: paL visible; all hA reads (L3) done

        // ---- P5 + P0: action, dynamics, STREL, next obs (threads 0..63) ----
        if (t < M) {
            float s0 = bm0, s1 = bm1;
            #pragma unroll
            for (int w = 0; w < 4; ++w) {
                s0 += paL[(w*2 + 0)*M + t];
                s1 += paL[(w*2 + 1)*M + t];
            }
            float ax = fminf(fmaxf(s0, -1.f), 1.f);
            float ay = fminf(fmaxf(s1, -1.f), 1.f);
            float vx = 2.f*ax + wx, vy = 2.f*ay + wy;
            #pragma unroll
            for (int s = 0; s < 4; ++s) {
                px = fminf(fmaxf(px + 0.0625f*vx, -4.f), 10.f);
                py = fminf(fmaxf(py + 0.0625f*vy, -4.f), 10.f);
            }
            float dx0 = px - 1.75f, dy0 = py - 1.75f;
            float dx1 = px - 1.75f, dy1 = py - 3.75f;
            float dx2 = px - 3.75f, dy2 = py - 2.00f;
            float c0 = sqrtf(dx0*dx0+dy0*dy0+1e-9f) - 0.38f;
            float c1 = sqrtf(dx1*dx1+dy1*dy1+1e-9f) - 0.42f;
            float c2 = sqrtf(dx2*dx2+dy2*dy2+1e-9f) - 0.34f;
            float cmin = fminf(c0, fminf(c1, c2));
            float ssum = expf(-50.f*(c0-cmin)) + expf(-50.f*(c1-cmin)) + expf(-50.f*(c2-cmin));
            float safe = cmin - logf(ssum)/50.f;
            float gdx = px - 4.f, gdy = py - 3.f;
            float reach = 0.45f - sqrtf(gdx*gdx+gdy*gdy+1e-9f);
            float xs = -8.f*safe;
            if (xs > mx_s) { sum_s = sum_s*expf(mx_s - xs) + 1.f; mx_s = xs; }
            else           { sum_s += expf(xs - mx_s); }
            float xr = 8.f*reach;
            if (xr > mx_r) { sum_r = sum_r*expf(mx_r - xr) + 1.f; mx_r = xr; }
            else           { sum_r += expf(xr - mx_r); }
            OBS_WRITE();   // obs for next step
        }
    }

    if (t < M) {
        float rs = -(mx_s + logf(sum_s)) * 0.125f;
        float rr =  (mx_r + logf(sum_r)) * 0.125f;
        float u0 = -8.f*rs, u1 = -8.f*rr;
        float mu = fmaxf(u0, u1);
        float rho = -(mu + logf(expf(u0-mu) + expf(u1-mu))) * 0.125f;
        out[blockIdx.x*M + t] = rho;
    }
}

} // namespace

extern "C" void kernel_launch(void* const* d_in, const int* in_sizes, int n_in,
                              void* d_out, int out_size, void* d_ws, size_t ws_size,
                              hipStream_t stream)
{
    const float* pos0 = (const float*)d_in[0];
    const float* wind = (const float*)d_in[1];
    const float* w1   = (const float*)d_in[2];
    const float* b1   = (const float*)d_in[3];
    const float* w2   = (const float*)d_in[4];
    const float* b2   = (const float*)d_in[5];
    const float* w3   = (const float*)d_in[6];
    const float* b3   = (const float*)d_in[7];
    const float* wmu  = (const float*)d_in[8];
    const float* bmu  = (const float*)d_in[9];
    float* out = (float*)d_out;
    f16* wp = (f16*)d_ws;   // 278528 f16 = 544 KB packed weights

    prep_kernel<<<544, 256, 0, stream>>>(w1, w2, w3, wp);

    const int B = in_sizes[0] / 2;     // 32768 agents
    const int blocks = B / M;          // 512 blocks, 2/CU, single pass
    rollout_kernel<<<blocks, NT, 0, stream>>>(pos0, wind, b1, b2, b3,
                                              wmu, bmu, wp, out);
}